// Round 12
// baseline (70.815 us; speedup 1.0000x reference)
//
#include <hip/hip_runtime.h>
#include <math.h>

#define B 8
#define N 2048
#define NP1 2049
#define FIN 128
#define FOUT 64
#define NS 0.2f
#define K 2048
#define KP1 2049
#define NCH 64
#define NCHP1 65
#define CHS 32

// monotone bucket map: bucketOf(x) < bucketOf(t) => x < t ; > => x >= t
__device__ __forceinline__ int bucketOf(float v) {
  int q = (int)floorf((v + 8.0f) * 128.0f);  // K=2048 over [-8,8]
  return min(max(q, 0), K - 1);
}

__device__ __forceinline__ int wscan_add_i(int v, int lane) {
#pragma unroll
  for (int off = 1; off < 64; off <<= 1) {
    int o = __shfl_up(v, off, 64);
    v += (lane >= off) ? o : 0;
  }
  return v;
}
__device__ __forceinline__ float wscan_add_f(float v, int lane) {
#pragma unroll
  for (int off = 1; off < 64; off <<= 1) {
    float o = __shfl_up(v, off, 64);
    v += (lane >= off) ? o : 0.f;
  }
  return v;
}

// ---------------------------------------------------------------------------
// K1: h = x@W, s1 = h.a1, s2 = h.a2. W column in 128 VGPRs; x read via
// wave-uniform address (readfirstlane-forced) -> scalar/broadcast loads,
// NO LDS, NO barrier. grid = 512 x 256 (wave = 8 rows).
// ---------------------------------------------------------------------------
#define RPB 32
__global__ __launch_bounds__(256, 2) void k_hs(
    const float* __restrict__ x, const float* __restrict__ W,
    const float* __restrict__ a, float* __restrict__ h,
    float* __restrict__ s1, float* __restrict__ s2) {
  const int lane = threadIdx.x & 63;
  const int wv = __builtin_amdgcn_readfirstlane(threadIdx.x >> 6);
  const int row0 = blockIdx.x * RPB + wv * 8;

  float w[FIN];
#pragma unroll
  for (int k = 0; k < FIN; ++k) w[k] = W[k * FOUT + lane];
  const float a1 = a[lane];
  const float a2 = a[FOUT + lane];

  for (int n = 0; n < 8; ++n) {
    const int row = row0 + n;
    const float* xr = x + (size_t)row * FIN;  // wave-uniform address
    float ac0 = 0.f, ac1 = 0.f, ac2 = 0.f, ac3 = 0.f;
#pragma unroll
    for (int k4 = 0; k4 < FIN; k4 += 4) {
      float4 xv = *(const float4*)(xr + k4);
      ac0 = fmaf(xv.x, w[k4 + 0], ac0);
      ac1 = fmaf(xv.y, w[k4 + 1], ac1);
      ac2 = fmaf(xv.z, w[k4 + 2], ac2);
      ac3 = fmaf(xv.w, w[k4 + 3], ac3);
    }
    const float acc = (ac0 + ac1) + (ac2 + ac3);
    h[(size_t)row * FOUT + lane] = acc;

    float v1 = acc * a1;
    float v2 = acc * a2;
#pragma unroll
    for (int off = 32; off > 0; off >>= 1) {
      v1 += __shfl_xor(v1, off, 64);
      v2 += __shfl_xor(v2, off, 64);
    }
    if (lane == 0) {
      s1[row] = v1;
      s2[row] = v2;
    }
  }
}

// ---------------------------------------------------------------------------
// K2: counting-sort bucketing (K=2048). grid = 2*B x 1024 threads.
// type 0 (s1): elemS1/elemU/elemUq in bucket order (exps inline), start1,
//              exclusive slot-prefix of u,uq ([N]=total).
// type 1 (s2): elemS2/idx2 in bucket order, start2.
// ---------------------------------------------------------------------------
__global__ __launch_bounds__(1024) void k_bucket(
    const float* __restrict__ s1, const float* __restrict__ s2,
    int* __restrict__ start1, float* __restrict__ elemS1,
    float* __restrict__ elemU, float* __restrict__ elemUq,
    float* __restrict__ slotPrefU, float* __restrict__ slotPrefQ,
    int* __restrict__ start2, float* __restrict__ elemS2,
    int* __restrict__ idx2) {
  __shared__ int cnt[K];     // 8 KB
  __shared__ int cur[K];     // 8 KB
  __shared__ float eS[N];    // 8 KB
  __shared__ float eU[N];    // 8 KB (type0)
  __shared__ float eQ[N];    // 8 KB (type0)
  __shared__ int eJ[N];      // 8 KB (type1)
  __shared__ int wtI[16];
  __shared__ float wtU[16], wtQ[16];

  const int type = blockIdx.x & 1;
  const int b = blockIdx.x >> 1;
  const int tid = threadIdx.x;
  const int lane = tid & 63;
  const int wv = tid >> 6;
  const float* key = (type ? s2 : s1) + b * N;

  cnt[tid] = 0;
  cnt[tid + 1024] = 0;
  __syncthreads();
  const float k0 = key[tid], k1 = key[tid + 1024];
  const int q0 = bucketOf(k0), q1 = bucketOf(k1);
  atomicAdd(&cnt[q0], 1);
  atomicAdd(&cnt[q1], 1);
  __syncthreads();

  // exclusive scan of cnt[2048] (2 entries/thread)
  {
    const int c0 = cnt[2 * tid], c1 = cnt[2 * tid + 1];
    const int loc = c0 + c1;
    const int incl = wscan_add_i(loc, lane);
    if (lane == 63) wtI[wv] = incl;
    __syncthreads();
    int cross = 0;
#pragma unroll
    for (int w = 0; w < 16; ++w) cross += (w < wv) ? wtI[w] : 0;
    const int ex = cross + incl - loc;
    cnt[2 * tid] = ex;       cnt[2 * tid + 1] = ex + c0;
    cur[2 * tid] = ex;       cur[2 * tid + 1] = ex + c0;
  }
  __syncthreads();

  // scatter (intra-bucket order arbitrary -> ulp-level reassociation only)
  if (type == 0) {
    int sl = atomicAdd(&cur[q0], 1);
    eS[sl] = k0; eU[sl] = expf(k0); eQ[sl] = expf(NS * k0);
    sl = atomicAdd(&cur[q1], 1);
    eS[sl] = k1; eU[sl] = expf(k1); eQ[sl] = expf(NS * k1);
  } else {
    int sl = atomicAdd(&cur[q0], 1);
    eS[sl] = k0; eJ[sl] = tid;
    sl = atomicAdd(&cur[q1], 1);
    eS[sl] = k1; eJ[sl] = tid + 1024;
  }
  __syncthreads();

  if (type == 1) {
    elemS2[b * N + tid] = eS[tid];
    elemS2[b * N + tid + 1024] = eS[tid + 1024];
    idx2[b * N + tid] = eJ[tid];
    idx2[b * N + tid + 1024] = eJ[tid + 1024];
    start2[b * KP1 + tid] = cnt[tid];
    start2[b * KP1 + tid + 1024] = cnt[tid + 1024];
    if (tid == 0) start2[b * KP1 + K] = N;
    return;
  }

  elemS1[b * N + tid] = eS[tid];
  elemS1[b * N + tid + 1024] = eS[tid + 1024];
  elemU[b * N + tid] = eU[tid];
  elemU[b * N + tid + 1024] = eU[tid + 1024];
  elemUq[b * N + tid] = eQ[tid];
  elemUq[b * N + tid + 1024] = eQ[tid + 1024];
  start1[b * KP1 + tid] = cnt[tid];
  start1[b * KP1 + tid + 1024] = cnt[tid + 1024];
  if (tid == 0) start1[b * KP1 + K] = N;

  // exclusive slot-prefix of eU,eQ (2 elems/thread)
  const float u0 = eU[2 * tid], u1 = eU[2 * tid + 1];
  const float g0 = eQ[2 * tid], g1 = eQ[2 * tid + 1];
  const float locU = u0 + u1, locQ = g0 + g1;
  const float iU = wscan_add_f(locU, lane);
  const float iQ = wscan_add_f(locQ, lane);
  if (lane == 63) { wtU[wv] = iU; wtQ[wv] = iQ; }
  __syncthreads();
  float crU = 0.f, crQ = 0.f, totU = 0.f, totQ = 0.f;
#pragma unroll
  for (int w = 0; w < 16; ++w) {
    const float au = wtU[w], aq = wtQ[w];
    crU += (w < wv) ? au : 0.f;
    crQ += (w < wv) ? aq : 0.f;
    totU += au; totQ += aq;
  }
  const float exU = crU + iU - locU, exQ = crQ + iQ - locQ;
  slotPrefU[b * NP1 + 2 * tid] = exU;
  slotPrefU[b * NP1 + 2 * tid + 1] = exU + u0;
  slotPrefQ[b * NP1 + 2 * tid] = exQ;
  slotPrefQ[b * NP1 + 2 * tid + 1] = exQ + g0;
  if (tid == 0) { slotPrefU[b * NP1 + N] = totU; slotPrefQ[b * NP1 + N] = totQ; }
}

// ---------------------------------------------------------------------------
// K3: fused {z + scan1}. grid = B*16 x 256 (wave = chunk of 32).
//  A) lanes 0-31: A/B for the chunk's 32 slots (boundary-bucket sweep) -> AB
//  B) gather hv[32] = h[idx2[s]][f], write hperm, chunk totals via __shfl.
// ---------------------------------------------------------------------------
__global__ __launch_bounds__(256) void k_scan1(
    const float* __restrict__ elemS1, const float* __restrict__ elemU,
    const float* __restrict__ elemUq, const float* __restrict__ slotPrefU,
    const float* __restrict__ slotPrefQ, const int* __restrict__ start1,
    const float* __restrict__ elemS2, const int* __restrict__ idx2,
    const float* __restrict__ h, float2* __restrict__ AB,
    float* __restrict__ hperm, float* __restrict__ ctA,
    float* __restrict__ ctB) {
  const int b = blockIdx.x >> 4;
  const int chunk = (blockIdx.x & 15) * 4 + (threadIdx.x >> 6);
  const int f = threadIdx.x & 63;
  const int s0 = chunk * CHS;

  // phase A: per-slot A/B
  float Aval = 0.f, Bval = 0.f;
  if (f < 32) {
    const int s = s0 + f;
    const float s2v = elemS2[b * N + s];
    const float t = -s2v;
    const int q = bucketOf(t);
    const int sb = start1[b * KP1 + q], se = start1[b * KP1 + q + 1];
    float Pu = slotPrefU[b * NP1 + sb];
    float Pq = slotPrefQ[b * NP1 + sb];
    for (int i = sb; i < se; ++i) {
      const bool lt = elemS1[b * N + i] < t;
      Pu += lt ? elemU[b * N + i] : 0.f;
      Pq += lt ? elemUq[b * N + i] : 0.f;
    }
    const float totU = slotPrefU[b * NP1 + N];
    const float E = expf(s2v), Eq = expf(NS * s2v);
    const float Z = E * (totU - Pu) + Eq * Pq;
    Aval = E / Z;
    Bval = Eq / Z;
    AB[b * N + s] = make_float2(Aval, Bval);
  }

  // phase B: gather h (independent chains), write hperm, chunk totals
  float hv[CHS];
#pragma unroll
  for (int g = 0; g < 2; ++g) {
#pragma unroll
    for (int rr = 0; rr < 16; ++rr) {
      const int s = s0 + g * 16 + rr;
      const int j = idx2[b * N + s];
      hv[g * 16 + rr] = h[((size_t)b * N + j) * FOUT + f];
    }
  }
  float ta = 0.f, tb = 0.f;
#pragma unroll
  for (int rr = 0; rr < CHS; ++rr) {
    hperm[((size_t)b * N + s0 + rr) * FOUT + f] = hv[rr];
    const float av = __shfl(Aval, rr, 64);
    const float bv = __shfl(Bval, rr, 64);
    ta = fmaf(av, hv[rr], ta);
    tb = fmaf(bv, hv[rr], tb);
  }
  ctA[(b * NCH + chunk) * FOUT + f] = ta;
  ctB[(b * NCH + chunk) * FOUT + f] = tb;
}

// ---------------------------------------------------------------------------
// K4: chunk-level exclusive prefixes PAx/PBx[65][64] per batch (registers
// only; 64 independent loads then in-reg prefix). grid = B x 128
// (wave 0: A, wave 1: B).
// ---------------------------------------------------------------------------
__global__ __launch_bounds__(128) void k_cpref(
    const float* __restrict__ ctA, const float* __restrict__ ctB,
    float* __restrict__ PAx, float* __restrict__ PBx) {
  const int b = blockIdx.x;
  const int f = threadIdx.x & 63;
  const int which = threadIdx.x >> 6;
  const float* src = which ? ctB : ctA;
  float* dst = which ? PBx : PAx;

  float v[NCH];
#pragma unroll
  for (int c = 0; c < NCH; ++c)
    v[c] = src[(b * NCH + c) * FOUT + f];
  float run = 0.f;
#pragma unroll
  for (int c = 0; c < NCH; ++c) {
    dst[((size_t)b * NCHP1 + c) * FOUT + f] = run;
    run += v[c];
  }
  dst[((size_t)b * NCHP1 + NCH) * FOUT + f] = run;
}

// ---------------------------------------------------------------------------
// K5: per row i (one wave): q = bucket(-s1_i); chunk-base sweep over hperm
//     (round-6 formula, now streaming): take slot if (s<sb)||(s2<t);
//     sa = totA - PAx[chb] - accA ; pb = PBx[chb] + accB. grid = B*N/4 x 256.
// ---------------------------------------------------------------------------
__global__ void k_out(const float* __restrict__ s1,
                      const int* __restrict__ start2,
                      const float* __restrict__ elemS2,
                      const float2* __restrict__ AB,
                      const float* __restrict__ hperm,
                      const float* __restrict__ PAx,
                      const float* __restrict__ PBx,
                      float* __restrict__ out) {
  const int wv = threadIdx.x >> 6;
  const int lane = threadIdx.x & 63;
  const int row = blockIdx.x * 4 + wv;
  const int b = row >> 11;
  const float s1v = s1[row];
  const float t = -s1v;
  const int q = bucketOf(t);
  const int sb = start2[b * KP1 + q];
  const int se = start2[b * KP1 + q + 1];
  const int chb = sb >> 5;  // CHS = 32

  const float PAv = PAx[((size_t)b * NCHP1 + chb) * FOUT + lane];
  const float PBv = PBx[((size_t)b * NCHP1 + chb) * FOUT + lane];
  const float totA = PAx[((size_t)b * NCHP1 + NCH) * FOUT + lane];

  float accA = 0.f, accB = 0.f;
  for (int s = chb * CHS; s < se; ++s) {
    const bool take = (s < sb) || (elemS2[b * N + s] < t);  // wave-uniform
    if (take) {
      const float2 ab = AB[b * N + s];
      const float hv = hperm[((size_t)b * N + s) * FOUT + lane];
      accA = fmaf(ab.x, hv, accA);
      accB = fmaf(ab.y, hv, accB);
    }
  }
  const float sa = totA - PAv - accA;
  const float pb = PBv + accB;
  const float uu = expf(s1v), uqv = expf(NS * s1v);
  const float v = uu * sa + uqv * pb;
  out[(size_t)row * FOUT + lane] = v >= 0.f ? v : NS * v;
}

extern "C" void kernel_launch(void* const* d_in, const int* in_sizes, int n_in,
                              void* d_out, int out_size, void* d_ws, size_t ws_size,
                              hipStream_t stream) {
  const float* x = (const float*)d_in[0];   // (8,2048,128)
  const float* W = (const float*)d_in[1];   // (128,64)
  const float* a = (const float*)d_in[2];   // (128,1)
  float* out = (float*)d_out;               // (8,2048,64)

  float* ws = (float*)d_ws;
  float* h = ws;                             // B*N*FOUT
  float* hperm = h + (size_t)B * N * FOUT;   // B*N*FOUT
  float* s1 = hperm + (size_t)B * N * FOUT;  // B*N each
  float* s2 = s1 + B * N;
  float* elemS1 = s2 + B * N;
  float* elemU = elemS1 + B * N;
  float* elemUq = elemU + B * N;
  float* elemS2 = elemUq + B * N;
  float* slotPrefU = elemS2 + B * N;         // B*NP1
  float* slotPrefQ = slotPrefU + B * NP1;
  float2* AB = (float2*)(slotPrefQ + B * NP1);  // B*N float2
  int* idx2 = (int*)(AB + (size_t)B * N);    // B*N
  int* start1 = idx2 + B * N;                // B*KP1
  int* start2 = start1 + B * KP1;
  float* ctA = (float*)(start2 + B * KP1);   // B*NCH*64
  float* ctB = ctA + (size_t)B * NCH * FOUT;
  float* PAx = ctB + (size_t)B * NCH * FOUT; // B*65*64
  float* PBx = PAx + (size_t)B * NCHP1 * FOUT;

  k_hs<<<B * N / RPB, 256, 0, stream>>>(x, W, a, h, s1, s2);
  k_bucket<<<2 * B, 1024, 0, stream>>>(s1, s2, start1, elemS1, elemU, elemUq,
                                       slotPrefU, slotPrefQ, start2, elemS2, idx2);
  k_scan1<<<B * 16, 256, 0, stream>>>(elemS1, elemU, elemUq, slotPrefU,
                                      slotPrefQ, start1, elemS2, idx2, h, AB,
                                      hperm, ctA, ctB);
  k_cpref<<<B, 128, 0, stream>>>(ctA, ctB, PAx, PBx);
  k_out<<<B * N / 4, 256, 0, stream>>>(s1, start2, elemS2, AB, hperm, PAx, PBx, out);
}

// Round 13
// 60.655 us; speedup vs baseline: 1.1675x; 1.1675x over previous
//
#include <hip/hip_runtime.h>
#include <math.h>

#define B 8
#define N 2048
#define NP1 2049
#define FIN 128
#define FOUT 64
#define NS 0.2f
#define K 2048
#define KP1 2049
#define NCH 64
#define CHS 32

// monotone bucket map: bucketOf(x) < bucketOf(t) => x < t ; > => x >= t
__device__ __forceinline__ int bucketOf(float v) {
  int q = (int)floorf((v + 8.0f) * 128.0f);  // K=2048 over [-8,8]
  return min(max(q, 0), K - 1);
}

__device__ __forceinline__ int wscan_add_i(int v, int lane) {
#pragma unroll
  for (int off = 1; off < 64; off <<= 1) {
    int o = __shfl_up(v, off, 64);
    v += (lane >= off) ? o : 0;
  }
  return v;
}
__device__ __forceinline__ float wscan_add_f(float v, int lane) {
#pragma unroll
  for (int off = 1; off < 64; off <<= 1) {
    float o = __shfl_up(v, off, 64);
    v += (lane >= off) ? o : 0.f;
  }
  return v;
}

// ---------------------------------------------------------------------------
// K1: h = x@W, s1 = h.a1, s2 = h.a2. W column in 128 VGPRs; x read via
// wave-uniform (readfirstlane-forced) address -> scalar/broadcast loads,
// no LDS, no barrier. grid = 512 x 256 (wave = 8 rows).
// [A/B: this is round-12's k_hs; rest of file is round-11 verbatim]
// ---------------------------------------------------------------------------
#define RPB 32
__global__ __launch_bounds__(256, 2) void k_hs(
    const float* __restrict__ x, const float* __restrict__ W,
    const float* __restrict__ a, float* __restrict__ h,
    float* __restrict__ s1, float* __restrict__ s2) {
  const int lane = threadIdx.x & 63;
  const int wv = __builtin_amdgcn_readfirstlane(threadIdx.x >> 6);
  const int row0 = blockIdx.x * RPB + wv * 8;

  float w[FIN];
#pragma unroll
  for (int k = 0; k < FIN; ++k) w[k] = W[k * FOUT + lane];
  const float a1 = a[lane];
  const float a2 = a[FOUT + lane];

  for (int n = 0; n < 8; ++n) {
    const int row = row0 + n;
    const float* xr = x + (size_t)row * FIN;  // wave-uniform address
    float ac0 = 0.f, ac1 = 0.f, ac2 = 0.f, ac3 = 0.f;
#pragma unroll
    for (int k4 = 0; k4 < FIN; k4 += 4) {
      float4 xv = *(const float4*)(xr + k4);
      ac0 = fmaf(xv.x, w[k4 + 0], ac0);
      ac1 = fmaf(xv.y, w[k4 + 1], ac1);
      ac2 = fmaf(xv.z, w[k4 + 2], ac2);
      ac3 = fmaf(xv.w, w[k4 + 3], ac3);
    }
    const float acc = (ac0 + ac1) + (ac2 + ac3);
    h[(size_t)row * FOUT + lane] = acc;

    float v1 = acc * a1;
    float v2 = acc * a2;
#pragma unroll
    for (int off = 32; off > 0; off >>= 1) {
      v1 += __shfl_xor(v1, off, 64);
      v2 += __shfl_xor(v2, off, 64);
    }
    if (lane == 0) {
      s1[row] = v1;
      s2[row] = v2;
    }
  }
}

// ---------------------------------------------------------------------------
// K2: counting-sort bucketing (K=2048). grid = 2*B x 1024 threads.
// type 0 (s1): elemS1/elemU/elemUq in bucket order (exps inline), start1,
//              exclusive slot-prefix of u,uq ([N]=total).
// type 1 (s2): elemS2/idx2 in bucket order, start2.
// ---------------------------------------------------------------------------
__global__ __launch_bounds__(1024) void k_bucket(
    const float* __restrict__ s1, const float* __restrict__ s2,
    int* __restrict__ start1, float* __restrict__ elemS1,
    float* __restrict__ elemU, float* __restrict__ elemUq,
    float* __restrict__ slotPrefU, float* __restrict__ slotPrefQ,
    int* __restrict__ start2, float* __restrict__ elemS2,
    int* __restrict__ idx2) {
  __shared__ int cnt[K];     // 8 KB
  __shared__ int cur[K];     // 8 KB
  __shared__ float eS[N];    // 8 KB
  __shared__ float eU[N];    // 8 KB (type0)
  __shared__ float eQ[N];    // 8 KB (type0)
  __shared__ int eJ[N];      // 8 KB (type1)
  __shared__ int wtI[16];
  __shared__ float wtU[16], wtQ[16];

  const int type = blockIdx.x & 1;
  const int b = blockIdx.x >> 1;
  const int tid = threadIdx.x;
  const int lane = tid & 63;
  const int wv = tid >> 6;
  const float* key = (type ? s2 : s1) + b * N;

  cnt[tid] = 0;
  cnt[tid + 1024] = 0;
  __syncthreads();
  const float k0 = key[tid], k1 = key[tid + 1024];
  const int q0 = bucketOf(k0), q1 = bucketOf(k1);
  atomicAdd(&cnt[q0], 1);
  atomicAdd(&cnt[q1], 1);
  __syncthreads();

  // exclusive scan of cnt[2048] (2 entries/thread)
  {
    const int c0 = cnt[2 * tid], c1 = cnt[2 * tid + 1];
    const int loc = c0 + c1;
    const int incl = wscan_add_i(loc, lane);
    if (lane == 63) wtI[wv] = incl;
    __syncthreads();
    int cross = 0;
#pragma unroll
    for (int w = 0; w < 16; ++w) cross += (w < wv) ? wtI[w] : 0;
    const int ex = cross + incl - loc;
    cnt[2 * tid] = ex;       cnt[2 * tid + 1] = ex + c0;
    cur[2 * tid] = ex;       cur[2 * tid + 1] = ex + c0;
  }
  __syncthreads();

  // scatter (intra-bucket order arbitrary -> ulp-level reassociation only)
  if (type == 0) {
    int sl = atomicAdd(&cur[q0], 1);
    eS[sl] = k0; eU[sl] = expf(k0); eQ[sl] = expf(NS * k0);
    sl = atomicAdd(&cur[q1], 1);
    eS[sl] = k1; eU[sl] = expf(k1); eQ[sl] = expf(NS * k1);
  } else {
    int sl = atomicAdd(&cur[q0], 1);
    eS[sl] = k0; eJ[sl] = tid;
    sl = atomicAdd(&cur[q1], 1);
    eS[sl] = k1; eJ[sl] = tid + 1024;
  }
  __syncthreads();

  if (type == 1) {
    elemS2[b * N + tid] = eS[tid];
    elemS2[b * N + tid + 1024] = eS[tid + 1024];
    idx2[b * N + tid] = eJ[tid];
    idx2[b * N + tid + 1024] = eJ[tid + 1024];
    start2[b * KP1 + tid] = cnt[tid];
    start2[b * KP1 + tid + 1024] = cnt[tid + 1024];
    if (tid == 0) start2[b * KP1 + K] = N;
    return;
  }

  elemS1[b * N + tid] = eS[tid];
  elemS1[b * N + tid + 1024] = eS[tid + 1024];
  elemU[b * N + tid] = eU[tid];
  elemU[b * N + tid + 1024] = eU[tid + 1024];
  elemUq[b * N + tid] = eQ[tid];
  elemUq[b * N + tid + 1024] = eQ[tid + 1024];
  start1[b * KP1 + tid] = cnt[tid];
  start1[b * KP1 + tid + 1024] = cnt[tid + 1024];
  if (tid == 0) start1[b * KP1 + K] = N;

  // exclusive slot-prefix of eU,eQ (2 elems/thread)
  const float u0 = eU[2 * tid], u1 = eU[2 * tid + 1];
  const float g0 = eQ[2 * tid], g1 = eQ[2 * tid + 1];
  const float locU = u0 + u1, locQ = g0 + g1;
  const float iU = wscan_add_f(locU, lane);
  const float iQ = wscan_add_f(locQ, lane);
  if (lane == 63) { wtU[wv] = iU; wtQ[wv] = iQ; }
  __syncthreads();
  float crU = 0.f, crQ = 0.f, totU = 0.f, totQ = 0.f;
#pragma unroll
  for (int w = 0; w < 16; ++w) {
    const float au = wtU[w], aq = wtQ[w];
    crU += (w < wv) ? au : 0.f;
    crQ += (w < wv) ? aq : 0.f;
    totU += au; totQ += aq;
  }
  const float exU = crU + iU - locU, exQ = crQ + iQ - locQ;
  slotPrefU[b * NP1 + 2 * tid] = exU;
  slotPrefU[b * NP1 + 2 * tid + 1] = exU + u0;
  slotPrefQ[b * NP1 + 2 * tid] = exQ;
  slotPrefQ[b * NP1 + 2 * tid + 1] = exQ + g0;
  if (tid == 0) { slotPrefU[b * NP1 + N] = totU; slotPrefQ[b * NP1 + N] = totQ; }
}

// ---------------------------------------------------------------------------
// K3: fused {z + scan1}, NO cross-block sync. grid = B*16 x 256.
//  A) lanes 0-31 of each wave: A/B for the chunk's 32 slots (boundary-bucket
//     sweep) -> AB
//  B) gather hv[32] = h[idx2[s]][f] (two 16-deep independent groups),
//     write hperm, chunk totals via __shfl of A/B.
// ---------------------------------------------------------------------------
__global__ __launch_bounds__(256) void k_scan1(
    const float* __restrict__ elemS1, const float* __restrict__ elemU,
    const float* __restrict__ elemUq, const float* __restrict__ slotPrefU,
    const float* __restrict__ slotPrefQ, const int* __restrict__ start1,
    const float* __restrict__ elemS2, const int* __restrict__ idx2,
    const float* __restrict__ h, float2* __restrict__ AB,
    float* __restrict__ hperm, float* __restrict__ ctA,
    float* __restrict__ ctB) {
  const int b = blockIdx.x >> 4;
  const int chunk = (blockIdx.x & 15) * 4 + (threadIdx.x >> 6);
  const int f = threadIdx.x & 63;
  const int s0 = chunk * CHS;

  // phase A: per-slot A/B (old k_z, verbatim)
  float Aval = 0.f, Bval = 0.f;
  if (f < 32) {
    const int s = s0 + f;
    const float s2v = elemS2[b * N + s];
    const float t = -s2v;
    const int q = bucketOf(t);
    const int sb = start1[b * KP1 + q], se = start1[b * KP1 + q + 1];
    float Pu = slotPrefU[b * NP1 + sb];
    float Pq = slotPrefQ[b * NP1 + sb];
    for (int i = sb; i < se; ++i) {
      const bool lt = elemS1[b * N + i] < t;
      Pu += lt ? elemU[b * N + i] : 0.f;
      Pq += lt ? elemUq[b * N + i] : 0.f;
    }
    const float totU = slotPrefU[b * NP1 + N];
    const float E = expf(s2v), Eq = expf(NS * s2v);
    const float Z = E * (totU - Pu) + Eq * Pq;
    Aval = E / Z;
    Bval = Eq / Z;
    AB[b * N + s] = make_float2(Aval, Bval);
  }

  // phase B: gather h (independent chains), write hperm, chunk totals
  float hv[CHS];
#pragma unroll
  for (int g = 0; g < 2; ++g) {
#pragma unroll
    for (int rr = 0; rr < 16; ++rr) {
      const int s = s0 + g * 16 + rr;
      const int j = idx2[b * N + s];
      hv[g * 16 + rr] = h[((size_t)b * N + j) * FOUT + f];
    }
  }
  float ta = 0.f, tb = 0.f;
#pragma unroll
  for (int rr = 0; rr < CHS; ++rr) {
    hperm[((size_t)b * N + s0 + rr) * FOUT + f] = hv[rr];
    const float av = __shfl(Aval, rr, 64);
    const float bv = __shfl(Bval, rr, 64);
    ta = fmaf(av, hv[rr], ta);
    tb = fmaf(bv, hv[rr], tb);
  }
  ctA[(b * NCH + chunk) * FOUT + f] = ta;
  ctB[(b * NCH + chunk) * FOUT + f] = tb;
}

// ---------------------------------------------------------------------------
// K4: slot-level PB (prefix of B*hperm) and SA (suffix of A*hperm) from chunk
// totals; all h access via hperm = streaming, no indirection. grid = B*16 x 256.
// ---------------------------------------------------------------------------
__global__ __launch_bounds__(256) void k_scan2(
    const float2* __restrict__ AB, const float* __restrict__ hperm,
    const float* __restrict__ ctA, const float* __restrict__ ctB,
    float* __restrict__ SA, float* __restrict__ PB) {
  __shared__ float cA[NCH * FOUT];  // 16 KB
  __shared__ float cB[NCH * FOUT];  // 16 KB
  const int b = blockIdx.x >> 4;
  const int chunk = (blockIdx.x & 15) * 4 + (threadIdx.x >> 6);
  const int f = threadIdx.x & 63;
  const int s0 = chunk * CHS;

  for (int t = threadIdx.x; t < NCH * FOUT; t += 256) {
    cA[t] = ctA[b * NCH * FOUT + t];
    cB[t] = ctB[b * NCH * FOUT + t];
  }
  __syncthreads();

  float offA = 0.f, offB = 0.f;
#pragma unroll 8
  for (int c2 = 0; c2 < NCH; ++c2) {
    const float va = cA[c2 * FOUT + f];
    const float vb = cB[c2 * FOUT + f];
    if (c2 > chunk) offA += va;
    if (c2 < chunk) offB += vb;
  }

  // forward prefix (PB)
  float run = offB;
#pragma unroll
  for (int g = 0; g < 2; ++g) {
    float hv[16]; float2 ab[16];
#pragma unroll
    for (int rr = 0; rr < 16; ++rr) {
      const int s = s0 + g * 16 + rr;
      hv[rr] = hperm[((size_t)b * N + s) * FOUT + f];
      ab[rr] = AB[b * N + s];
    }
#pragma unroll
    for (int rr = 0; rr < 16; ++rr) {
      run = fmaf(ab[rr].y, hv[rr], run);
      PB[((size_t)b * NP1 + s0 + g * 16 + rr + 1) * FOUT + f] = run;
    }
  }
  // backward suffix (SA)
  run = offA;
#pragma unroll
  for (int g = 1; g >= 0; --g) {
    float hv[16]; float2 ab[16];
#pragma unroll
    for (int rr = 0; rr < 16; ++rr) {
      const int s = s0 + g * 16 + rr;
      hv[rr] = hperm[((size_t)b * N + s) * FOUT + f];
      ab[rr] = AB[b * N + s];
    }
#pragma unroll
    for (int rr = 15; rr >= 0; --rr) {
      run = fmaf(ab[rr].x, hv[rr], run);
      SA[((size_t)b * NP1 + s0 + g * 16 + rr) * FOUT + f] = run;
    }
  }
  if (chunk == 0) {
    PB[((size_t)b * NP1 + 0) * FOUT + f] = 0.f;
    SA[((size_t)b * NP1 + N) * FOUT + f] = 0.f;
  }
}

// ---------------------------------------------------------------------------
// K5: per row i (one wave): q = bucket(-s1_i); sa = SA[se], pb = PB[sb],
//     boundary sweep over hperm (direct, no idx2 chain). grid = B*N/4 x 256.
// ---------------------------------------------------------------------------
__global__ void k_out(const float* __restrict__ s1,
                      const int* __restrict__ start2,
                      const float* __restrict__ elemS2,
                      const float2* __restrict__ AB,
                      const float* __restrict__ hperm,
                      const float* __restrict__ SA,
                      const float* __restrict__ PB,
                      float* __restrict__ out) {
  const int wv = threadIdx.x >> 6;
  const int lane = threadIdx.x & 63;
  const int row = blockIdx.x * 4 + wv;
  const int b = row >> 11;
  const float s1v = s1[row];
  const float t = -s1v;
  const int q = bucketOf(t);
  const int sb = start2[b * KP1 + q];
  const int se = start2[b * KP1 + q + 1];

  float sa = SA[((size_t)b * NP1 + se) * FOUT + lane];  // all buckets > q
  float pb = PB[((size_t)b * NP1 + sb) * FOUT + lane];  // all buckets < q
  for (int s = sb; s < se; ++s) {
    const float s2v = elemS2[b * N + s];
    const float2 ab = AB[b * N + s];
    const float hv = hperm[((size_t)b * N + s) * FOUT + lane];
    if (s2v >= t) sa = fmaf(ab.x, hv, sa);
    else          pb = fmaf(ab.y, hv, pb);
  }
  const float uu = expf(s1v), uqv = expf(NS * s1v);
  const float v = uu * sa + uqv * pb;
  out[(size_t)row * FOUT + lane] = v >= 0.f ? v : NS * v;
}

extern "C" void kernel_launch(void* const* d_in, const int* in_sizes, int n_in,
                              void* d_out, int out_size, void* d_ws, size_t ws_size,
                              hipStream_t stream) {
  const float* x = (const float*)d_in[0];   // (8,2048,128)
  const float* W = (const float*)d_in[1];   // (128,64)
  const float* a = (const float*)d_in[2];   // (128,1)
  float* out = (float*)d_out;               // (8,2048,64)

  float* ws = (float*)d_ws;
  float* h = ws;                             // B*N*FOUT
  float* hperm = h + (size_t)B * N * FOUT;   // B*N*FOUT
  float* s1 = hperm + (size_t)B * N * FOUT;  // B*N each
  float* s2 = s1 + B * N;
  float* elemS1 = s2 + B * N;
  float* elemU = elemS1 + B * N;
  float* elemUq = elemU + B * N;
  float* elemS2 = elemUq + B * N;
  float* slotPrefU = elemS2 + B * N;         // B*NP1
  float* slotPrefQ = slotPrefU + B * NP1;
  float2* AB = (float2*)(slotPrefQ + B * NP1);  // B*N float2
  int* idx2 = (int*)(AB + (size_t)B * N);    // B*N
  int* start1 = idx2 + B * N;                // B*KP1
  int* start2 = start1 + B * KP1;
  float* ctA = (float*)(start2 + B * KP1);   // B*NCH*64
  float* ctB = ctA + (size_t)B * NCH * FOUT;
  float* SA = ctB + (size_t)B * NCH * FOUT;  // B*NP1*64
  float* PB = SA + (size_t)B * NP1 * FOUT;

  k_hs<<<B * N / RPB, 256, 0, stream>>>(x, W, a, h, s1, s2);
  k_bucket<<<2 * B, 1024, 0, stream>>>(s1, s2, start1, elemS1, elemU, elemUq,
                                       slotPrefU, slotPrefQ, start2, elemS2, idx2);
  k_scan1<<<B * 16, 256, 0, stream>>>(elemS1, elemU, elemUq, slotPrefU,
                                      slotPrefQ, start1, elemS2, idx2, h, AB,
                                      hperm, ctA, ctB);
  k_scan2<<<B * 16, 256, 0, stream>>>(AB, hperm, ctA, ctB, SA, PB);
  k_out<<<B * N / 4, 256, 0, stream>>>(s1, start2, elemS2, AB, hperm, SA, PB, out);
}

// Round 14
// 55.436 us; speedup vs baseline: 1.2774x; 1.0941x over previous
//
#include <hip/hip_runtime.h>
#include <math.h>

#define B 8
#define N 2048
#define NP1 2049
#define FIN 128
#define FOUT 64
#define NS 0.2f
#define K 2048
#define KP1 2049
#define NCH 64
#define CHS 32
#define NQ 512     // N/4 sub-slot boundaries
#define NQ1 513

// monotone bucket map: bucketOf(x) < bucketOf(t) => x < t ; > => x >= t
__device__ __forceinline__ int bucketOf(float v) {
  int q = (int)floorf((v + 8.0f) * 128.0f);  // K=2048 over [-8,8]
  return min(max(q, 0), K - 1);
}

__device__ __forceinline__ int wscan_add_i(int v, int lane) {
#pragma unroll
  for (int off = 1; off < 64; off <<= 1) {
    int o = __shfl_up(v, off, 64);
    v += (lane >= off) ? o : 0;
  }
  return v;
}
__device__ __forceinline__ float wscan_add_f(float v, int lane) {
#pragma unroll
  for (int off = 1; off < 64; off <<= 1) {
    float o = __shfl_up(v, off, 64);
    v += (lane >= off) ? o : 0.f;
  }
  return v;
}

// ---------------------------------------------------------------------------
// K1: h = x@W, s1 = h.a1, s2 = h.a2. W column in 128 VGPRs, x in LDS.
// grid = 512 x 256 (block = 32 rows, wave = 8 rows).  [round-11 proven form:
// LDS-staged x; scalar-x variant measured +7.2us worse in round 13]
// ---------------------------------------------------------------------------
#define RPB 32
__global__ __launch_bounds__(256, 2) void k_hs(
    const float* __restrict__ x, const float* __restrict__ W,
    const float* __restrict__ a, float* __restrict__ h,
    float* __restrict__ s1, float* __restrict__ s2) {
  __shared__ float xs[RPB * FIN];  // 16 KB
  const int row0 = blockIdx.x * RPB;
  const int lane = threadIdx.x & 63;
  const int wv = threadIdx.x >> 6;

  {
    const float4* src = (const float4*)(x + (size_t)row0 * FIN);
    float4* dst = (float4*)xs;
#pragma unroll
    for (int t = 0; t < 4; ++t)
      dst[threadIdx.x + 256 * t] = src[threadIdx.x + 256 * t];
  }

  float w[FIN];
#pragma unroll
  for (int k = 0; k < FIN; ++k) w[k] = W[k * FOUT + lane];
  const float a1 = a[lane];
  const float a2 = a[FOUT + lane];
  __syncthreads();

  for (int n = 0; n < 8; ++n) {
    const int r = wv * 8 + n;
    const float* xr = xs + r * FIN;
    float ac0 = 0.f, ac1 = 0.f, ac2 = 0.f, ac3 = 0.f;
#pragma unroll
    for (int k4 = 0; k4 < FIN; k4 += 4) {
      float4 xv = *(const float4*)(xr + k4);
      ac0 = fmaf(xv.x, w[k4 + 0], ac0);
      ac1 = fmaf(xv.y, w[k4 + 1], ac1);
      ac2 = fmaf(xv.z, w[k4 + 2], ac2);
      ac3 = fmaf(xv.w, w[k4 + 3], ac3);
    }
    const float acc = (ac0 + ac1) + (ac2 + ac3);
    const int row = row0 + r;
    h[(size_t)row * FOUT + lane] = acc;

    float v1 = acc * a1;
    float v2 = acc * a2;
#pragma unroll
    for (int off = 32; off > 0; off >>= 1) {
      v1 += __shfl_xor(v1, off, 64);
      v2 += __shfl_xor(v2, off, 64);
    }
    if (lane == 0) {
      s1[row] = v1;
      s2[row] = v2;
    }
  }
}

// ---------------------------------------------------------------------------
// K2: counting-sort bucketing (K=2048). grid = 2*B x 1024 threads.
// type 0 (s1): elemS1/elemU/elemUq in bucket order (exps inline), start1,
//              exclusive slot-prefix of u,uq ([N]=total).
// type 1 (s2): elemS2/idx2 in bucket order, start2.
// ---------------------------------------------------------------------------
__global__ __launch_bounds__(1024) void k_bucket(
    const float* __restrict__ s1, const float* __restrict__ s2,
    int* __restrict__ start1, float* __restrict__ elemS1,
    float* __restrict__ elemU, float* __restrict__ elemUq,
    float* __restrict__ slotPrefU, float* __restrict__ slotPrefQ,
    int* __restrict__ start2, float* __restrict__ elemS2,
    int* __restrict__ idx2) {
  __shared__ int cnt[K];     // 8 KB
  __shared__ int cur[K];     // 8 KB
  __shared__ float eS[N];    // 8 KB
  __shared__ float eU[N];    // 8 KB (type0)
  __shared__ float eQ[N];    // 8 KB (type0)
  __shared__ int eJ[N];      // 8 KB (type1)
  __shared__ int wtI[16];
  __shared__ float wtU[16], wtQ[16];

  const int type = blockIdx.x & 1;
  const int b = blockIdx.x >> 1;
  const int tid = threadIdx.x;
  const int lane = tid & 63;
  const int wv = tid >> 6;
  const float* key = (type ? s2 : s1) + b * N;

  cnt[tid] = 0;
  cnt[tid + 1024] = 0;
  __syncthreads();
  const float k0 = key[tid], k1 = key[tid + 1024];
  const int q0 = bucketOf(k0), q1 = bucketOf(k1);
  atomicAdd(&cnt[q0], 1);
  atomicAdd(&cnt[q1], 1);
  __syncthreads();

  // exclusive scan of cnt[2048] (2 entries/thread)
  {
    const int c0 = cnt[2 * tid], c1 = cnt[2 * tid + 1];
    const int loc = c0 + c1;
    const int incl = wscan_add_i(loc, lane);
    if (lane == 63) wtI[wv] = incl;
    __syncthreads();
    int cross = 0;
#pragma unroll
    for (int w = 0; w < 16; ++w) cross += (w < wv) ? wtI[w] : 0;
    const int ex = cross + incl - loc;
    cnt[2 * tid] = ex;       cnt[2 * tid + 1] = ex + c0;
    cur[2 * tid] = ex;       cur[2 * tid + 1] = ex + c0;
  }
  __syncthreads();

  // scatter (intra-bucket order arbitrary -> ulp-level reassociation only)
  if (type == 0) {
    int sl = atomicAdd(&cur[q0], 1);
    eS[sl] = k0; eU[sl] = expf(k0); eQ[sl] = expf(NS * k0);
    sl = atomicAdd(&cur[q1], 1);
    eS[sl] = k1; eU[sl] = expf(k1); eQ[sl] = expf(NS * k1);
  } else {
    int sl = atomicAdd(&cur[q0], 1);
    eS[sl] = k0; eJ[sl] = tid;
    sl = atomicAdd(&cur[q1], 1);
    eS[sl] = k1; eJ[sl] = tid + 1024;
  }
  __syncthreads();

  if (type == 1) {
    elemS2[b * N + tid] = eS[tid];
    elemS2[b * N + tid + 1024] = eS[tid + 1024];
    idx2[b * N + tid] = eJ[tid];
    idx2[b * N + tid + 1024] = eJ[tid + 1024];
    start2[b * KP1 + tid] = cnt[tid];
    start2[b * KP1 + tid + 1024] = cnt[tid + 1024];
    if (tid == 0) start2[b * KP1 + K] = N;
    return;
  }

  elemS1[b * N + tid] = eS[tid];
  elemS1[b * N + tid + 1024] = eS[tid + 1024];
  elemU[b * N + tid] = eU[tid];
  elemU[b * N + tid + 1024] = eU[tid + 1024];
  elemUq[b * N + tid] = eQ[tid];
  elemUq[b * N + tid + 1024] = eQ[tid + 1024];
  start1[b * KP1 + tid] = cnt[tid];
  start1[b * KP1 + tid + 1024] = cnt[tid + 1024];
  if (tid == 0) start1[b * KP1 + K] = N;

  // exclusive slot-prefix of eU,eQ (2 elems/thread)
  const float u0 = eU[2 * tid], u1 = eU[2 * tid + 1];
  const float g0 = eQ[2 * tid], g1 = eQ[2 * tid + 1];
  const float locU = u0 + u1, locQ = g0 + g1;
  const float iU = wscan_add_f(locU, lane);
  const float iQ = wscan_add_f(locQ, lane);
  if (lane == 63) { wtU[wv] = iU; wtQ[wv] = iQ; }
  __syncthreads();
  float crU = 0.f, crQ = 0.f, totU = 0.f, totQ = 0.f;
#pragma unroll
  for (int w = 0; w < 16; ++w) {
    const float au = wtU[w], aq = wtQ[w];
    crU += (w < wv) ? au : 0.f;
    crQ += (w < wv) ? aq : 0.f;
    totU += au; totQ += aq;
  }
  const float exU = crU + iU - locU, exQ = crQ + iQ - locQ;
  slotPrefU[b * NP1 + 2 * tid] = exU;
  slotPrefU[b * NP1 + 2 * tid + 1] = exU + u0;
  slotPrefQ[b * NP1 + 2 * tid] = exQ;
  slotPrefQ[b * NP1 + 2 * tid + 1] = exQ + g0;
  if (tid == 0) { slotPrefU[b * NP1 + N] = totU; slotPrefQ[b * NP1 + N] = totQ; }
}

// ---------------------------------------------------------------------------
// K3: fused {z + scan1}, NO cross-block sync. grid = B*16 x 256.
//  A) lanes 0-31 of each wave: A/B for the chunk's 32 slots -> AB
//  B) gather hv[32] = h[idx2[s]][f], write hperm, chunk totals via __shfl.
// ---------------------------------------------------------------------------
__global__ __launch_bounds__(256) void k_scan1(
    const float* __restrict__ elemS1, const float* __restrict__ elemU,
    const float* __restrict__ elemUq, const float* __restrict__ slotPrefU,
    const float* __restrict__ slotPrefQ, const int* __restrict__ start1,
    const float* __restrict__ elemS2, const int* __restrict__ idx2,
    const float* __restrict__ h, float2* __restrict__ AB,
    float* __restrict__ hperm, float* __restrict__ ctA,
    float* __restrict__ ctB) {
  const int b = blockIdx.x >> 4;
  const int chunk = (blockIdx.x & 15) * 4 + (threadIdx.x >> 6);
  const int f = threadIdx.x & 63;
  const int s0 = chunk * CHS;

  // phase A: per-slot A/B
  float Aval = 0.f, Bval = 0.f;
  if (f < 32) {
    const int s = s0 + f;
    const float s2v = elemS2[b * N + s];
    const float t = -s2v;
    const int q = bucketOf(t);
    const int sb = start1[b * KP1 + q], se = start1[b * KP1 + q + 1];
    float Pu = slotPrefU[b * NP1 + sb];
    float Pq = slotPrefQ[b * NP1 + sb];
    for (int i = sb; i < se; ++i) {
      const bool lt = elemS1[b * N + i] < t;
      Pu += lt ? elemU[b * N + i] : 0.f;
      Pq += lt ? elemUq[b * N + i] : 0.f;
    }
    const float totU = slotPrefU[b * NP1 + N];
    const float E = expf(s2v), Eq = expf(NS * s2v);
    const float Z = E * (totU - Pu) + Eq * Pq;
    Aval = E / Z;
    Bval = Eq / Z;
    AB[b * N + s] = make_float2(Aval, Bval);
  }

  // phase B: gather h (independent chains), write hperm, chunk totals
  float hv[CHS];
#pragma unroll
  for (int g = 0; g < 2; ++g) {
#pragma unroll
    for (int rr = 0; rr < 16; ++rr) {
      const int s = s0 + g * 16 + rr;
      const int j = idx2[b * N + s];
      hv[g * 16 + rr] = h[((size_t)b * N + j) * FOUT + f];
    }
  }
  float ta = 0.f, tb = 0.f;
#pragma unroll
  for (int rr = 0; rr < CHS; ++rr) {
    hperm[((size_t)b * N + s0 + rr) * FOUT + f] = hv[rr];
    const float av = __shfl(Aval, rr, 64);
    const float bv = __shfl(Bval, rr, 64);
    ta = fmaf(av, hv[rr], ta);
    tb = fmaf(bv, hv[rr], tb);
  }
  ctA[(b * NCH + chunk) * FOUT + f] = ta;
  ctB[(b * NCH + chunk) * FOUT + f] = tb;
}

// ---------------------------------------------------------------------------
// K4: G=4 sub-slot prefixes. PB4[c][f] = prefix of B*hperm over slots < 4c;
// SA4[c][f] = suffix of A*hperm over slots >= 4c. 4x less store traffic than
// slot-level. grid = B*16 x 256.
// ---------------------------------------------------------------------------
__global__ __launch_bounds__(256) void k_scan2(
    const float2* __restrict__ AB, const float* __restrict__ hperm,
    const float* __restrict__ ctA, const float* __restrict__ ctB,
    float* __restrict__ SA4, float* __restrict__ PB4) {
  __shared__ float cA[NCH * FOUT];  // 16 KB
  __shared__ float cB[NCH * FOUT];  // 16 KB
  const int b = blockIdx.x >> 4;
  const int chunk = (blockIdx.x & 15) * 4 + (threadIdx.x >> 6);
  const int f = threadIdx.x & 63;
  const int s0 = chunk * CHS;

  for (int t = threadIdx.x; t < NCH * FOUT; t += 256) {
    cA[t] = ctA[b * NCH * FOUT + t];
    cB[t] = ctB[b * NCH * FOUT + t];
  }
  __syncthreads();

  float offA = 0.f, offB = 0.f;
#pragma unroll 8
  for (int c2 = 0; c2 < NCH; ++c2) {
    const float va = cA[c2 * FOUT + f];
    const float vb = cB[c2 * FOUT + f];
    if (c2 > chunk) offA += va;
    if (c2 < chunk) offB += vb;
  }

  // forward prefix (PB4 at every 4th slot boundary)
  float run = offB;
#pragma unroll
  for (int g = 0; g < 2; ++g) {
    float hv[16]; float2 ab[16];
#pragma unroll
    for (int rr = 0; rr < 16; ++rr) {
      const int s = s0 + g * 16 + rr;
      hv[rr] = hperm[((size_t)b * N + s) * FOUT + f];
      ab[rr] = AB[b * N + s];
    }
#pragma unroll
    for (int rr = 0; rr < 16; ++rr) {
      const int s = s0 + g * 16 + rr;
      if ((s & 3) == 0)
        PB4[((size_t)b * NQ1 + (s >> 2)) * FOUT + f] = run;
      run = fmaf(ab[rr].y, hv[rr], run);
    }
  }
  if (chunk == NCH - 1)
    PB4[((size_t)b * NQ1 + NQ) * FOUT + f] = run;  // total

  // backward suffix (SA4)
  run = offA;
#pragma unroll
  for (int g = 1; g >= 0; --g) {
    float hv[16]; float2 ab[16];
#pragma unroll
    for (int rr = 0; rr < 16; ++rr) {
      const int s = s0 + g * 16 + rr;
      hv[rr] = hperm[((size_t)b * N + s) * FOUT + f];
      ab[rr] = AB[b * N + s];
    }
#pragma unroll
    for (int rr = 15; rr >= 0; --rr) {
      const int s = s0 + g * 16 + rr;
      run = fmaf(ab[rr].x, hv[rr], run);
      if ((s & 3) == 0)
        SA4[((size_t)b * NQ1 + (s >> 2)) * FOUT + f] = run;
    }
  }
  if (chunk == NCH - 1)
    SA4[((size_t)b * NQ1 + NQ) * FOUT + f] = 0.f;
}

// ---------------------------------------------------------------------------
// K5: per row i (one wave): q = bucket(-s1_i); window [4*floor(sb/4),
// 4*ceil(se/4)) swept with compare-only classification (exact by bucket
// monotonicity: s<sb => s2<t, s>=se => s2>=t). pb = PB4[sb>>2] + B-side;
// sa = SA4[ceil(se/4)] + A-side. grid = B*N/4 x 256.
// ---------------------------------------------------------------------------
__global__ void k_out(const float* __restrict__ s1,
                      const int* __restrict__ start2,
                      const float* __restrict__ elemS2,
                      const float2* __restrict__ AB,
                      const float* __restrict__ hperm,
                      const float* __restrict__ SA4,
                      const float* __restrict__ PB4,
                      float* __restrict__ out) {
  const int wv = threadIdx.x >> 6;
  const int lane = threadIdx.x & 63;
  const int row = blockIdx.x * 4 + wv;
  const int b = row >> 11;
  const float s1v = s1[row];
  const float t = -s1v;
  const int q = bucketOf(t);
  const int sb = start2[b * KP1 + q];
  const int se = start2[b * KP1 + q + 1];
  const int lo = (sb >> 2) << 2;
  const int hiq = (se + 3) >> 2;
  const int hi = hiq << 2;

  float pb = PB4[((size_t)b * NQ1 + (sb >> 2)) * FOUT + lane];
  float sa = SA4[((size_t)b * NQ1 + hiq) * FOUT + lane];
  for (int s = lo; s < hi; ++s) {
    const float s2v = elemS2[b * N + s];
    const float2 ab = AB[b * N + s];
    const float hv = hperm[((size_t)b * N + s) * FOUT + lane];
    if (s2v < t) pb = fmaf(ab.y, hv, pb);
    else         sa = fmaf(ab.x, hv, sa);
  }
  const float uu = expf(s1v), uqv = expf(NS * s1v);
  const float v = uu * sa + uqv * pb;
  out[(size_t)row * FOUT + lane] = v >= 0.f ? v : NS * v;
}

extern "C" void kernel_launch(void* const* d_in, const int* in_sizes, int n_in,
                              void* d_out, int out_size, void* d_ws, size_t ws_size,
                              hipStream_t stream) {
  const float* x = (const float*)d_in[0];   // (8,2048,128)
  const float* W = (const float*)d_in[1];   // (128,64)
  const float* a = (const float*)d_in[2];   // (128,1)
  float* out = (float*)d_out;               // (8,2048,64)

  float* ws = (float*)d_ws;
  float* h = ws;                             // B*N*FOUT
  float* hperm = h + (size_t)B * N * FOUT;   // B*N*FOUT
  float* s1 = hperm + (size_t)B * N * FOUT;  // B*N each
  float* s2 = s1 + B * N;
  float* elemS1 = s2 + B * N;
  float* elemU = elemS1 + B * N;
  float* elemUq = elemU + B * N;
  float* elemS2 = elemUq + B * N;
  float* slotPrefU = elemS2 + B * N;         // B*NP1
  float* slotPrefQ = slotPrefU + B * NP1;
  float2* AB = (float2*)(slotPrefQ + B * NP1);  // B*N float2
  int* idx2 = (int*)(AB + (size_t)B * N);    // B*N
  int* start1 = idx2 + B * N;                // B*KP1
  int* start2 = start1 + B * KP1;
  float* ctA = (float*)(start2 + B * KP1);   // B*NCH*64
  float* ctB = ctA + (size_t)B * NCH * FOUT;
  float* SA4 = ctB + (size_t)B * NCH * FOUT; // B*NQ1*64
  float* PB4 = SA4 + (size_t)B * NQ1 * FOUT;

  k_hs<<<B * N / RPB, 256, 0, stream>>>(x, W, a, h, s1, s2);
  k_bucket<<<2 * B, 1024, 0, stream>>>(s1, s2, start1, elemS1, elemU, elemUq,
                                       slotPrefU, slotPrefQ, start2, elemS2, idx2);
  k_scan1<<<B * 16, 256, 0, stream>>>(elemS1, elemU, elemUq, slotPrefU,
                                      slotPrefQ, start1, elemS2, idx2, h, AB,
                                      hperm, ctA, ctB);
  k_scan2<<<B * 16, 256, 0, stream>>>(AB, hperm, ctA, ctB, SA4, PB4);
  k_out<<<B * N / 4, 256, 0, stream>>>(s1, start2, elemS2, AB, hperm, SA4, PB4, out);
}

// Round 15
// 53.425 us; speedup vs baseline: 1.3255x; 1.0377x over previous
//
#include <hip/hip_runtime.h>
#include <math.h>

#define B 8
#define N 2048
#define NP1 2049
#define FIN 128
#define FOUT 64
#define NS 0.2f
#define K 2048
#define KP1 2049
#define NCH 64
#define CHS 32

// monotone bucket map: bucketOf(x) < bucketOf(t) => x < t ; > => x >= t
__device__ __forceinline__ int bucketOf(float v) {
  int q = (int)floorf((v + 8.0f) * 128.0f);  // K=2048 over [-8,8]
  return min(max(q, 0), K - 1);
}

__device__ __forceinline__ int wscan_add_i(int v, int lane) {
#pragma unroll
  for (int off = 1; off < 64; off <<= 1) {
    int o = __shfl_up(v, off, 64);
    v += (lane >= off) ? o : 0;
  }
  return v;
}
__device__ __forceinline__ float wscan_add_f(float v, int lane) {
#pragma unroll
  for (int off = 1; off < 64; off <<= 1) {
    float o = __shfl_up(v, off, 64);
    v += (lane >= off) ? o : 0.f;
  }
  return v;
}

// ---------------------------------------------------------------------------
// K1: h = x@W, s1 = h.a1, s2 = h.a2. W column in 128 VGPRs, x in LDS.
// grid = 512 x 256 (block = 32 rows, wave = 8 rows).
// [proven: LDS-staged x; scalar-x variant was +7.2us (r13)]
// ---------------------------------------------------------------------------
#define RPB 32
__global__ __launch_bounds__(256, 2) void k_hs(
    const float* __restrict__ x, const float* __restrict__ W,
    const float* __restrict__ a, float* __restrict__ h,
    float* __restrict__ s1, float* __restrict__ s2) {
  __shared__ float xs[RPB * FIN];  // 16 KB
  const int row0 = blockIdx.x * RPB;
  const int lane = threadIdx.x & 63;
  const int wv = threadIdx.x >> 6;

  {
    const float4* src = (const float4*)(x + (size_t)row0 * FIN);
    float4* dst = (float4*)xs;
#pragma unroll
    for (int t = 0; t < 4; ++t)
      dst[threadIdx.x + 256 * t] = src[threadIdx.x + 256 * t];
  }

  float w[FIN];
#pragma unroll
  for (int k = 0; k < FIN; ++k) w[k] = W[k * FOUT + lane];
  const float a1 = a[lane];
  const float a2 = a[FOUT + lane];
  __syncthreads();

  for (int n = 0; n < 8; ++n) {
    const int r = wv * 8 + n;
    const float* xr = xs + r * FIN;
    float ac0 = 0.f, ac1 = 0.f, ac2 = 0.f, ac3 = 0.f;
#pragma unroll
    for (int k4 = 0; k4 < FIN; k4 += 4) {
      float4 xv = *(const float4*)(xr + k4);
      ac0 = fmaf(xv.x, w[k4 + 0], ac0);
      ac1 = fmaf(xv.y, w[k4 + 1], ac1);
      ac2 = fmaf(xv.z, w[k4 + 2], ac2);
      ac3 = fmaf(xv.w, w[k4 + 3], ac3);
    }
    const float acc = (ac0 + ac1) + (ac2 + ac3);
    const int row = row0 + r;
    h[(size_t)row * FOUT + lane] = acc;

    float v1 = acc * a1;
    float v2 = acc * a2;
#pragma unroll
    for (int off = 32; off > 0; off >>= 1) {
      v1 += __shfl_xor(v1, off, 64);
      v2 += __shfl_xor(v2, off, 64);
    }
    if (lane == 0) {
      s1[row] = v1;
      s2[row] = v2;
    }
  }
}

// ---------------------------------------------------------------------------
// K2: counting-sort bucketing (K=2048). grid = 2*B x 1024 threads.
// type 0 (s1): elemS1/elemU/elemUq in bucket order (exps inline), start1,
//              exclusive slot-prefix of u,uq ([N]=total).
// type 1 (s2): elemS2/idx2 in bucket order, start2.
// ---------------------------------------------------------------------------
__global__ __launch_bounds__(1024) void k_bucket(
    const float* __restrict__ s1, const float* __restrict__ s2,
    int* __restrict__ start1, float* __restrict__ elemS1,
    float* __restrict__ elemU, float* __restrict__ elemUq,
    float* __restrict__ slotPrefU, float* __restrict__ slotPrefQ,
    int* __restrict__ start2, float* __restrict__ elemS2,
    int* __restrict__ idx2) {
  __shared__ int cnt[K];     // 8 KB
  __shared__ int cur[K];     // 8 KB
  __shared__ float eS[N];    // 8 KB
  __shared__ float eU[N];    // 8 KB (type0)
  __shared__ float eQ[N];    // 8 KB (type0)
  __shared__ int eJ[N];      // 8 KB (type1)
  __shared__ int wtI[16];
  __shared__ float wtU[16], wtQ[16];

  const int type = blockIdx.x & 1;
  const int b = blockIdx.x >> 1;
  const int tid = threadIdx.x;
  const int lane = tid & 63;
  const int wv = tid >> 6;
  const float* key = (type ? s2 : s1) + b * N;

  cnt[tid] = 0;
  cnt[tid + 1024] = 0;
  __syncthreads();
  const float k0 = key[tid], k1 = key[tid + 1024];
  const int q0 = bucketOf(k0), q1 = bucketOf(k1);
  atomicAdd(&cnt[q0], 1);
  atomicAdd(&cnt[q1], 1);
  __syncthreads();

  // exclusive scan of cnt[2048] (2 entries/thread)
  {
    const int c0 = cnt[2 * tid], c1 = cnt[2 * tid + 1];
    const int loc = c0 + c1;
    const int incl = wscan_add_i(loc, lane);
    if (lane == 63) wtI[wv] = incl;
    __syncthreads();
    int cross = 0;
#pragma unroll
    for (int w = 0; w < 16; ++w) cross += (w < wv) ? wtI[w] : 0;
    const int ex = cross + incl - loc;
    cnt[2 * tid] = ex;       cnt[2 * tid + 1] = ex + c0;
    cur[2 * tid] = ex;       cur[2 * tid + 1] = ex + c0;
  }
  __syncthreads();

  // scatter (intra-bucket order arbitrary -> ulp-level reassociation only)
  if (type == 0) {
    int sl = atomicAdd(&cur[q0], 1);
    eS[sl] = k0; eU[sl] = expf(k0); eQ[sl] = expf(NS * k0);
    sl = atomicAdd(&cur[q1], 1);
    eS[sl] = k1; eU[sl] = expf(k1); eQ[sl] = expf(NS * k1);
  } else {
    int sl = atomicAdd(&cur[q0], 1);
    eS[sl] = k0; eJ[sl] = tid;
    sl = atomicAdd(&cur[q1], 1);
    eS[sl] = k1; eJ[sl] = tid + 1024;
  }
  __syncthreads();

  if (type == 1) {
    elemS2[b * N + tid] = eS[tid];
    elemS2[b * N + tid + 1024] = eS[tid + 1024];
    idx2[b * N + tid] = eJ[tid];
    idx2[b * N + tid + 1024] = eJ[tid + 1024];
    start2[b * KP1 + tid] = cnt[tid];
    start2[b * KP1 + tid + 1024] = cnt[tid + 1024];
    if (tid == 0) start2[b * KP1 + K] = N;
    return;
  }

  elemS1[b * N + tid] = eS[tid];
  elemS1[b * N + tid + 1024] = eS[tid + 1024];
  elemU[b * N + tid] = eU[tid];
  elemU[b * N + tid + 1024] = eU[tid + 1024];
  elemUq[b * N + tid] = eQ[tid];
  elemUq[b * N + tid + 1024] = eQ[tid + 1024];
  start1[b * KP1 + tid] = cnt[tid];
  start1[b * KP1 + tid + 1024] = cnt[tid + 1024];
  if (tid == 0) start1[b * KP1 + K] = N;

  // exclusive slot-prefix of eU,eQ (2 elems/thread)
  const float u0 = eU[2 * tid], u1 = eU[2 * tid + 1];
  const float g0 = eQ[2 * tid], g1 = eQ[2 * tid + 1];
  const float locU = u0 + u1, locQ = g0 + g1;
  const float iU = wscan_add_f(locU, lane);
  const float iQ = wscan_add_f(locQ, lane);
  if (lane == 63) { wtU[wv] = iU; wtQ[wv] = iQ; }
  __syncthreads();
  float crU = 0.f, crQ = 0.f, totU = 0.f, totQ = 0.f;
#pragma unroll
  for (int w = 0; w < 16; ++w) {
    const float au = wtU[w], aq = wtQ[w];
    crU += (w < wv) ? au : 0.f;
    crQ += (w < wv) ? aq : 0.f;
    totU += au; totQ += aq;
  }
  const float exU = crU + iU - locU, exQ = crQ + iQ - locQ;
  slotPrefU[b * NP1 + 2 * tid] = exU;
  slotPrefU[b * NP1 + 2 * tid + 1] = exU + u0;
  slotPrefQ[b * NP1 + 2 * tid] = exQ;
  slotPrefQ[b * NP1 + 2 * tid + 1] = exQ + g0;
  if (tid == 0) { slotPrefU[b * NP1 + N] = totU; slotPrefQ[b * NP1 + N] = totQ; }
}

// ---------------------------------------------------------------------------
// K3: fused {z + scan1}, NO cross-block sync. grid = B*16 x 256.
//  A) lanes 0-31 of each wave: A/B for the chunk's 32 slots (boundary-bucket
//     sweep) -> AB
//  B) gather hv[32] = h[idx2[s]][f] (two 16-deep independent groups),
//     write hperm, chunk totals via __shfl of A/B.
// ---------------------------------------------------------------------------
__global__ __launch_bounds__(256) void k_scan1(
    const float* __restrict__ elemS1, const float* __restrict__ elemU,
    const float* __restrict__ elemUq, const float* __restrict__ slotPrefU,
    const float* __restrict__ slotPrefQ, const int* __restrict__ start1,
    const float* __restrict__ elemS2, const int* __restrict__ idx2,
    const float* __restrict__ h, float2* __restrict__ AB,
    float* __restrict__ hperm, float* __restrict__ ctA,
    float* __restrict__ ctB) {
  const int b = blockIdx.x >> 4;
  const int chunk = (blockIdx.x & 15) * 4 + (threadIdx.x >> 6);
  const int f = threadIdx.x & 63;
  const int s0 = chunk * CHS;

  // phase A: per-slot A/B
  float Aval = 0.f, Bval = 0.f;
  if (f < 32) {
    const int s = s0 + f;
    const float s2v = elemS2[b * N + s];
    const float t = -s2v;
    const int q = bucketOf(t);
    const int sb = start1[b * KP1 + q], se = start1[b * KP1 + q + 1];
    float Pu = slotPrefU[b * NP1 + sb];
    float Pq = slotPrefQ[b * NP1 + sb];
    for (int i = sb; i < se; ++i) {
      const bool lt = elemS1[b * N + i] < t;
      Pu += lt ? elemU[b * N + i] : 0.f;
      Pq += lt ? elemUq[b * N + i] : 0.f;
    }
    const float totU = slotPrefU[b * NP1 + N];
    const float E = expf(s2v), Eq = expf(NS * s2v);
    const float Z = E * (totU - Pu) + Eq * Pq;
    Aval = E / Z;
    Bval = Eq / Z;
    AB[b * N + s] = make_float2(Aval, Bval);
  }

  // phase B: gather h (independent chains), write hperm, chunk totals
  float hv[CHS];
#pragma unroll
  for (int g = 0; g < 2; ++g) {
#pragma unroll
    for (int rr = 0; rr < 16; ++rr) {
      const int s = s0 + g * 16 + rr;
      const int j = idx2[b * N + s];
      hv[g * 16 + rr] = h[((size_t)b * N + j) * FOUT + f];
    }
  }
  float ta = 0.f, tb = 0.f;
#pragma unroll
  for (int rr = 0; rr < CHS; ++rr) {
    hperm[((size_t)b * N + s0 + rr) * FOUT + f] = hv[rr];
    const float av = __shfl(Aval, rr, 64);
    const float bv = __shfl(Bval, rr, 64);
    ta = fmaf(av, hv[rr], ta);
    tb = fmaf(bv, hv[rr], tb);
  }
  ctA[(b * NCH + chunk) * FOUT + f] = ta;
  ctB[(b * NCH + chunk) * FOUT + f] = tb;
}

// ---------------------------------------------------------------------------
// K4: slot-level PB (prefix of B*hperm) and SA (suffix of A*hperm) from chunk
// totals; all h access via hperm = streaming, no indirection. grid = B*16 x 256.
// ---------------------------------------------------------------------------
__global__ __launch_bounds__(256) void k_scan2(
    const float2* __restrict__ AB, const float* __restrict__ hperm,
    const float* __restrict__ ctA, const float* __restrict__ ctB,
    float* __restrict__ SA, float* __restrict__ PB) {
  __shared__ float cA[NCH * FOUT];  // 16 KB
  __shared__ float cB[NCH * FOUT];  // 16 KB
  const int b = blockIdx.x >> 4;
  const int chunk = (blockIdx.x & 15) * 4 + (threadIdx.x >> 6);
  const int f = threadIdx.x & 63;
  const int s0 = chunk * CHS;

  for (int t = threadIdx.x; t < NCH * FOUT; t += 256) {
    cA[t] = ctA[b * NCH * FOUT + t];
    cB[t] = ctB[b * NCH * FOUT + t];
  }
  __syncthreads();

  float offA = 0.f, offB = 0.f;
#pragma unroll 8
  for (int c2 = 0; c2 < NCH; ++c2) {
    const float va = cA[c2 * FOUT + f];
    const float vb = cB[c2 * FOUT + f];
    if (c2 > chunk) offA += va;
    if (c2 < chunk) offB += vb;
  }

  // forward prefix (PB)
  float run = offB;
#pragma unroll
  for (int g = 0; g < 2; ++g) {
    float hv[16]; float2 ab[16];
#pragma unroll
    for (int rr = 0; rr < 16; ++rr) {
      const int s = s0 + g * 16 + rr;
      hv[rr] = hperm[((size_t)b * N + s) * FOUT + f];
      ab[rr] = AB[b * N + s];
    }
#pragma unroll
    for (int rr = 0; rr < 16; ++rr) {
      run = fmaf(ab[rr].y, hv[rr], run);
      PB[((size_t)b * NP1 + s0 + g * 16 + rr + 1) * FOUT + f] = run;
    }
  }
  // backward suffix (SA)
  run = offA;
#pragma unroll
  for (int g = 1; g >= 0; --g) {
    float hv[16]; float2 ab[16];
#pragma unroll
    for (int rr = 0; rr < 16; ++rr) {
      const int s = s0 + g * 16 + rr;
      hv[rr] = hperm[((size_t)b * N + s) * FOUT + f];
      ab[rr] = AB[b * N + s];
    }
#pragma unroll
    for (int rr = 15; rr >= 0; --rr) {
      run = fmaf(ab[rr].x, hv[rr], run);
      SA[((size_t)b * NP1 + s0 + g * 16 + rr) * FOUT + f] = run;
    }
  }
  if (chunk == 0) {
    PB[((size_t)b * NP1 + 0) * FOUT + f] = 0.f;
    SA[((size_t)b * NP1 + N) * FOUT + f] = 0.f;
  }
}

// ---------------------------------------------------------------------------
// K5: per row i (one wave): q = bucket(-s1_i); sa = SA[se], pb = PB[sb],
//     boundary sweep over hperm (direct, no idx2 chain). grid = B*N/4 x 256.
// ---------------------------------------------------------------------------
__global__ void k_out(const float* __restrict__ s1,
                      const int* __restrict__ start2,
                      const float* __restrict__ elemS2,
                      const float2* __restrict__ AB,
                      const float* __restrict__ hperm,
                      const float* __restrict__ SA,
                      const float* __restrict__ PB,
                      float* __restrict__ out) {
  const int wv = threadIdx.x >> 6;
  const int lane = threadIdx.x & 63;
  const int row = blockIdx.x * 4 + wv;
  const int b = row >> 11;
  const float s1v = s1[row];
  const float t = -s1v;
  const int q = bucketOf(t);
  const int sb = start2[b * KP1 + q];
  const int se = start2[b * KP1 + q + 1];

  float sa = SA[((size_t)b * NP1 + se) * FOUT + lane];  // all buckets > q
  float pb = PB[((size_t)b * NP1 + sb) * FOUT + lane];  // all buckets < q
  for (int s = sb; s < se; ++s) {
    const float s2v = elemS2[b * N + s];
    const float2 ab = AB[b * N + s];
    const float hv = hperm[((size_t)b * N + s) * FOUT + lane];
    if (s2v >= t) sa = fmaf(ab.x, hv, sa);
    else          pb = fmaf(ab.y, hv, pb);
  }
  const float uu = expf(s1v), uqv = expf(NS * s1v);
  const float v = uu * sa + uqv * pb;
  out[(size_t)row * FOUT + lane] = v >= 0.f ? v : NS * v;
}

extern "C" void kernel_launch(void* const* d_in, const int* in_sizes, int n_in,
                              void* d_out, int out_size, void* d_ws, size_t ws_size,
                              hipStream_t stream) {
  const float* x = (const float*)d_in[0];   // (8,2048,128)
  const float* W = (const float*)d_in[1];   // (128,64)
  const float* a = (const float*)d_in[2];   // (128,1)
  float* out = (float*)d_out;               // (8,2048,64)

  float* ws = (float*)d_ws;
  float* h = ws;                             // B*N*FOUT
  float* hperm = h + (size_t)B * N * FOUT;   // B*N*FOUT
  float* s1 = hperm + (size_t)B * N * FOUT;  // B*N each
  float* s2 = s1 + B * N;
  float* elemS1 = s2 + B * N;
  float* elemU = elemS1 + B * N;
  float* elemUq = elemU + B * N;
  float* elemS2 = elemUq + B * N;
  float* slotPrefU = elemS2 + B * N;         // B*NP1
  float* slotPrefQ = slotPrefU + B * NP1;
  float2* AB = (float2*)(slotPrefQ + B * NP1);  // B*N float2
  int* idx2 = (int*)(AB + (size_t)B * N);    // B*N
  int* start1 = idx2 + B * N;                // B*KP1
  int* start2 = start1 + B * KP1;
  float* ctA = (float*)(start2 + B * KP1);   // B*NCH*64
  float* ctB = ctA + (size_t)B * NCH * FOUT;
  float* SA = ctB + (size_t)B * NCH * FOUT;  // B*NP1*64
  float* PB = SA + (size_t)B * NP1 * FOUT;

  k_hs<<<B * N / RPB, 256, 0, stream>>>(x, W, a, h, s1, s2);
  k_bucket<<<2 * B, 1024, 0, stream>>>(s1, s2, start1, elemS1, elemU, elemUq,
                                       slotPrefU, slotPrefQ, start2, elemS2, idx2);
  k_scan1<<<B * 16, 256, 0, stream>>>(elemS1, elemU, elemUq, slotPrefU,
                                      slotPrefQ, start1, elemS2, idx2, h, AB,
                                      hperm, ctA, ctB);
  k_scan2<<<B * 16, 256, 0, stream>>>(AB, hperm, ctA, ctB, SA, PB);
  k_out<<<B * N / 4, 256, 0, stream>>>(s1, start2, elemS2, AB, hperm, SA, PB, out);
}